// Round 4
// baseline (809.633 us; speedup 1.0000x reference)
//
#include <hip/hip_runtime.h>
#include <cfloat>
#include <math.h>

// Problem constants
#define NB 2
#define SS 2048
#define HIDN 2048
#define NHH 16
#define DH 128
#define SBI 204       // int(0.1*S)
#define KEEPEND 1844  // S - int(0.1*S)
#define NREC 128      // MERGE_BUDGET
#define NTOPK 16

typedef short bf16x8 __attribute__((ext_vector_type(8)));
typedef short bf16x4 __attribute__((ext_vector_type(4)));
typedef float f32x4  __attribute__((ext_vector_type(4)));
typedef unsigned short ushort8_v __attribute__((ext_vector_type(8)));
typedef unsigned short ushort4_v __attribute__((ext_vector_type(4)));

#define GLOBAL_AS __attribute__((address_space(1)))
#define LDS_AS    __attribute__((address_space(3)))

__device__ __forceinline__ void async16(const unsigned short* g, unsigned short* l){
  __builtin_amdgcn_global_load_lds((const GLOBAL_AS void*)g, (LDS_AS void*)l, 16, 0, 0);
}

__device__ __forceinline__ unsigned short f2bf(float x){
  union { float f; unsigned u; } cv; cv.f = x;
  unsigned u = cv.u;
  return (unsigned short)((u + 0x7fffu + ((u >> 16) & 1u)) >> 16);
}
__device__ __forceinline__ float bf2f(unsigned short u){
  union { unsigned u; float f; } cv; cv.u = ((unsigned)u) << 16;
  return cv.f;
}

__constant__ const float SCALE_QK = 0.08838834764831845f;   // 1/sqrt(128)
__constant__ const float SCALE2   = 0.12752551286084322f;   // SCALE_QK * log2(e)
__constant__ const float LOG2E    = 1.4426950408889634f;

__global__ void k_zero(float* __restrict__ p, int n){
  int i = blockIdx.x * 256 + threadIdx.x;
  if (i < n) p[i] = 0.f;
}

// ---------------- fp32 -> bf16 convert (8 elems/thread) -----------------------------------
__global__ void k_f2bf(const float* __restrict__ src, unsigned short* __restrict__ dst, int n8){
  int i = blockIdx.x * 256 + threadIdx.x;
  if (i >= n8) return;
  const float4* s = (const float4*)src + (size_t)i * 2;
  float4 a = s[0], b = s[1];
  ushort8_v r;
  r[0] = f2bf(a.x); r[1] = f2bf(a.y); r[2] = f2bf(a.z); r[3] = f2bf(a.w);
  r[4] = f2bf(b.x); r[5] = f2bf(b.y); r[6] = f2bf(b.z); r[7] = f2bf(b.w);
  *(ushort8_v*)(dst + (size_t)i * 8) = r;
}

// ---------------- bf16 MFMA GEMM: QKV variant, writes bf16 q/k/v with fused RoPE ----------
__global__ __launch_bounds__(256) void k_gemm_qkv(
    const unsigned short* __restrict__ A, const unsigned short* __restrict__ W,
    const float* __restrict__ bias, const int* __restrict__ pos,
    unsigned short* __restrict__ q, unsigned short* __restrict__ k,
    unsigned short* __restrict__ v)
{
  __shared__ __align__(16) unsigned short As[128 * 32];
  __shared__ __align__(16) unsigned short Bs[128 * 32];
  const int tid  = threadIdx.x;
  const int lane = tid & 63, w = tid >> 6;
  const int wm = w >> 1, wn = w & 1;
  const int quad = lane >> 4, m16 = lane & 15;
  const int cb   = blockIdx.x;
  const int row0 = blockIdx.y * 128;
  const int col0 = cb * 128;

  const int srow = tid >> 2;
  const int scol = (tid & 3) * 8;
  const unsigned short* ga = A + (size_t)(row0 + srow) * HIDN + scol;
  const unsigned short* gb = W + (size_t)(col0 + srow) * HIDN + scol;
  unsigned short* la = As + tid * 8;
  unsigned short* lb = Bs + tid * 8;

  f32x4 acc[4][4];
  #pragma unroll
  for (int i = 0; i < 4; ++i)
    #pragma unroll
    for (int j = 0; j < 4; ++j)
      acc[i][j] = (f32x4){0.f, 0.f, 0.f, 0.f};

  for (int k0 = 0; k0 < HIDN; k0 += 32){
    __syncthreads();
    async16(ga + k0,             la);
    async16(ga + k0 + 64 * HIDN, la + 64 * 32);
    async16(gb + k0,             lb);
    async16(gb + k0 + 64 * HIDN, lb + 64 * 32);
    __syncthreads();
    bf16x8 af[4], bf[4];
    #pragma unroll
    for (int j = 0; j < 4; ++j)
      bf[j] = *(const bf16x8*)(Bs + (wn * 64 + j * 16 + m16) * 32 + quad * 8);
    #pragma unroll
    for (int i = 0; i < 4; ++i)
      af[i] = *(const bf16x8*)(As + (wm * 64 + i * 16 + m16) * 32 + quad * 8);
    #pragma unroll
    for (int i = 0; i < 4; ++i)
      #pragma unroll
      for (int j = 0; j < 4; ++j)
        acc[i][j] = __builtin_amdgcn_mfma_f32_16x16x32_bf16(af[i], bf[j], acc[i][j], 0, 0, 0);
  }

  const int h  = cb / 3, r3 = cb - 3 * (cb / 3);
  unsigned short* dst = (r3 == 0) ? q : ((r3 == 1) ? k : v);
  const bool do_rope = (r3 < 2) && (wn == 0);
  const float invf = __expf(-(float)m16 * 0.5756462732485115f); // ln(10000)/16

  #pragma unroll
  for (int i = 0; i < 4; ++i){
    #pragma unroll
    for (int reg = 0; reg < 4; ++reg){
      const int mr = row0 + wm * 64 + i * 16 + quad * 4 + reg;
      const int b_ = mr >> 11, s_ = mr & (SS - 1);
      unsigned short* drow = dst + (size_t)((b_ * NHH + h) * SS + s_) * DH;
      float vals[4];
      #pragma unroll
      for (int j = 0; j < 4; ++j)
        vals[j] = acc[i][j][reg] + bias[col0 + wn * 64 + j * 16 + m16];
      if (do_rope){
        float sn, cs;
        const float p = (float)pos[b_ * SS + s_];
        sincosf(p * invf, &sn, &cs);
        const float x0 = vals[0], x1 = vals[1];
        vals[0] = x0 * cs - x1 * sn;
        vals[1] = x1 * cs + x0 * sn;
      }
      #pragma unroll
      for (int j = 0; j < 4; ++j)
        drow[wn * 64 + j * 16 + m16] = f2bf(vals[j]);
    }
  }
}

// Dense variant: C = A @ W^T + bias (A bf16, fp32 out)
__global__ __launch_bounds__(256) void k_gemm_dense(
    const unsigned short* __restrict__ A, const unsigned short* __restrict__ W,
    const float* __restrict__ bias, float* __restrict__ out)
{
  __shared__ __align__(16) unsigned short As[128 * 32];
  __shared__ __align__(16) unsigned short Bs[128 * 32];
  const int tid  = threadIdx.x;
  const int lane = tid & 63, w = tid >> 6;
  const int wm = w >> 1, wn = w & 1;
  const int quad = lane >> 4, m16 = lane & 15;
  const int row0 = blockIdx.y * 128;
  const int col0 = blockIdx.x * 128;

  const int srow = tid >> 2;
  const int scol = (tid & 3) * 8;
  const unsigned short* ga = A + (size_t)(row0 + srow) * HIDN + scol;
  const unsigned short* gb = W + (size_t)(col0 + srow) * HIDN + scol;
  unsigned short* la = As + tid * 8;
  unsigned short* lb = Bs + tid * 8;

  f32x4 acc[4][4];
  #pragma unroll
  for (int i = 0; i < 4; ++i)
    #pragma unroll
    for (int j = 0; j < 4; ++j)
      acc[i][j] = (f32x4){0.f, 0.f, 0.f, 0.f};

  for (int k0 = 0; k0 < HIDN; k0 += 32){
    __syncthreads();
    async16(ga + k0,             la);
    async16(ga + k0 + 64 * HIDN, la + 64 * 32);
    async16(gb + k0,             lb);
    async16(gb + k0 + 64 * HIDN, lb + 64 * 32);
    __syncthreads();
    bf16x8 af[4], bf[4];
    #pragma unroll
    for (int j = 0; j < 4; ++j)
      bf[j] = *(const bf16x8*)(Bs + (wn * 64 + j * 16 + m16) * 32 + quad * 8);
    #pragma unroll
    for (int i = 0; i < 4; ++i)
      af[i] = *(const bf16x8*)(As + (wm * 64 + i * 16 + m16) * 32 + quad * 8);
    #pragma unroll
    for (int i = 0; i < 4; ++i)
      #pragma unroll
      for (int j = 0; j < 4; ++j)
        acc[i][j] = __builtin_amdgcn_mfma_f32_16x16x32_bf16(af[i], bf[j], acc[i][j], 0, 0, 0);
  }

  #pragma unroll
  for (int i = 0; i < 4; ++i){
    #pragma unroll
    for (int reg = 0; reg < 4; ++reg){
      const int mr = row0 + wm * 64 + i * 16 + quad * 4 + reg;
      #pragma unroll
      for (int j = 0; j < 4; ++j){
        const int c = col0 + wn * 64 + j * 16 + m16;
        out[(size_t)mr * HIDN + c] = acc[i][j][reg] + bias[c];
      }
    }
  }
}

// ---------------- V transpose with k-permutation: Vt[bh][d][perm(s)] ----------------------
// perm within each 64-chunk: slot(k) = (k&15)*4 + (k>>4), k = s & 63.
__global__ __launch_bounds__(256) void k_vt(
    const unsigned short* __restrict__ v, unsigned short* __restrict__ vt)
{
  __shared__ unsigned short ld[64 * 136];
  const int tid = threadIdx.x;
  const int st = blockIdx.x;
  const int bh = blockIdx.y;
  const int s0 = st * 64;
  #pragma unroll
  for (int it = 0; it < 4; ++it){
    int vv = tid + it * 256;
    int row = vv >> 4, cv = (vv & 15) * 8;
    *(bf16x8*)(ld + row * 136 + cv) =
        *(const bf16x8*)(v + (size_t)(bh * SS + s0 + row) * DH + cv);
  }
  __syncthreads();
  const int d = tid >> 1, h2 = tid & 1;
  unsigned short* orow = vt + (size_t)(bh * DH + d) * SS + s0 + h2 * 32;
  #pragma unroll
  for (int g = 0; g < 4; ++g){
    ushort8_v pk;
    #pragma unroll
    for (int e = 0; e < 8; ++e){
      const int slot = h2 * 32 + g * 8 + e;
      const int kl = (slot & 3) * 16 + (slot >> 2);   // inverse perm
      pk[e] = ld[kl * 136 + d];
    }
    *(ushort8_v*)(orow + g * 8) = pk;
  }
}

// ---------------- Fused two-pass MFMA flash attention -------------------------------------
// 512 blocks flat; heavy-first + heavy/light pairing. 4 waves; wave w owns q rows
// [w*32, w*32+32). exp2-domain softmax, per-lane online (m,l), acol fused.
__global__ __launch_bounds__(256, 3) void k_fattn(
    const unsigned short* __restrict__ qg, const unsigned short* __restrict__ kg,
    const unsigned short* __restrict__ vtg, const float* __restrict__ amask,
    unsigned short* __restrict__ attn_out, float* __restrict__ acol,
    float* __restrict__ colsum_all, float* __restrict__ colsum_recent)
{
  __shared__ __align__(16) unsigned short Ks[64 * 132];
  __shared__ __align__(16) unsigned short Ps[128 * 68];
  __shared__ __align__(16) unsigned short Vt[128 * 68];
  __shared__ float colbuf[64];

  const int tid  = threadIdx.x;
  const int lane = tid & 63, w = tid >> 6;
  const int quad = lane >> 4, m16 = lane & 15;
  const int f = blockIdx.x;
  const int bh = f & 31;
  const int qt = (f < 256) ? (15 - (f >> 5)) : ((f - 256) >> 5);
  const int b_ = bh >> 4, h_ = bh & 15;
  const int q0 = qt * 128;
  const int rbase = w * 32;
  const unsigned short* qb  = qg  + (size_t)bh * SS * DH;
  const unsigned short* kb  = kg  + (size_t)bh * SS * DH;
  const unsigned short* vtb = vtg + (size_t)bh * DH * SS;
  const float* mk = amask + b_ * SS;
  const int nkt = 2 * qt + 2;

  // Q fragments in registers
  bf16x8 Qf[2][4];
  #pragma unroll
  for (int i = 0; i < 2; ++i)
    #pragma unroll
    for (int ds = 0; ds < 4; ++ds)
      Qf[i][ds] = *(const bf16x8*)(qb + (size_t)(q0 + rbase + i * 16 + m16) * DH + ds * 32 + quad * 8);

  // ---------------- pass A: per-lane online m,l (log2 domain) ----------------
  float m_ln[2][4], l_ln[2][4];
  #pragma unroll
  for (int i = 0; i < 2; ++i)
    #pragma unroll
    for (int r = 0; r < 4; ++r){ m_ln[i][r] = -FLT_MAX; l_ln[i][r] = 0.f; }

  for (int kt = 0; kt < nkt; ++kt){
    const int kt64 = kt * 64;
    __syncthreads();
    #pragma unroll
    for (int it = 0; it < 4; ++it){
      int vv = tid + it * 256;
      int row = vv >> 4, cv = (vv & 15) * 8;
      *(bf16x8*)(Ks + row * 132 + cv) =
          *(const bf16x8*)(kb + (size_t)(kt64 + row) * DH + cv);
    }
    __syncthreads();
    f32x4 acc[2][4];
    #pragma unroll
    for (int i = 0; i < 2; ++i)
      #pragma unroll
      for (int j = 0; j < 4; ++j) acc[i][j] = (f32x4){0.f,0.f,0.f,0.f};
    #pragma unroll
    for (int ds = 0; ds < 4; ++ds){
      bf16x8 Bf[4];
      #pragma unroll
      for (int j = 0; j < 4; ++j)
        Bf[j] = *(const bf16x8*)(Ks + (j * 16 + m16) * 132 + ds * 32 + quad * 8);
      #pragma unroll
      for (int i = 0; i < 2; ++i)
        #pragma unroll
        for (int j = 0; j < 4; ++j)
          acc[i][j] = __builtin_amdgcn_mfma_f32_16x16x32_bf16(Qf[i][ds], Bf[j], acc[i][j], 0, 0, 0);
    }
    float mk2v[4];
    #pragma unroll
    for (int j = 0; j < 4; ++j) mk2v[j] = mk[kt64 + j * 16 + m16] * LOG2E;
    const bool full = (kt64 + 63 <= q0 + rbase);
    #pragma unroll
    for (int i = 0; i < 2; ++i){
      #pragma unroll
      for (int r = 0; r < 4; ++r){
        float s[4];
        #pragma unroll
        for (int j = 0; j < 4; ++j) s[j] = acc[i][j][r] * SCALE2 + mk2v[j];
        if (!full){
          const int qrow = q0 + rbase + i * 16 + quad * 4 + r;
          #pragma unroll
          for (int j = 0; j < 4; ++j)
            if (kt64 + j * 16 + m16 > qrow) s[j] = -FLT_MAX;
        }
        float tmax = fmaxf(fmaxf(s[0], s[1]), fmaxf(s[2], s[3]));
        if (tmax > -1e37f){
          const float mn = fmaxf(m_ln[i][r], tmax);
          float ts = exp2f(s[0]-mn) + exp2f(s[1]-mn) + exp2f(s[2]-mn) + exp2f(s[3]-mn);
          l_ln[i][r] = l_ln[i][r] * exp2f(m_ln[i][r] - mn) + ts;
          m_ln[i][r] = mn;
        }
      }
    }
  }

  // cross-lane merge (4-step butterfly over the 16 column lanes)
  float m_run[2][4], rl[2][4];
  #pragma unroll
  for (int i = 0; i < 2; ++i)
    #pragma unroll
    for (int r = 0; r < 4; ++r){
      float m = m_ln[i][r], l = l_ln[i][r];
      #pragma unroll
      for (int d2 = 1; d2 < 16; d2 <<= 1){
        const float mo = __shfl_xor(m, d2);
        const float lo = __shfl_xor(l, d2);
        const float mn = fmaxf(m, mo);
        l = l * exp2f(m - mn) + lo * exp2f(mo - mn);
        m = mn;
      }
      m_run[i][r] = m;
      rl[i][r] = 1.f / l;
    }

  // ---------------- pass B: exact P, colsums, acol, PV ----------------
  f32x4 o[2][8];
  #pragma unroll
  for (int i = 0; i < 2; ++i)
    #pragma unroll
    for (int jd = 0; jd < 8; ++jd) o[i][jd] = (f32x4){0.f,0.f,0.f,0.f};

  for (int kt = 0; kt < nkt; ++kt){
    const int kt64 = kt * 64;
    __syncthreads();   // prev PV + colbuf flush done
    #pragma unroll
    for (int it = 0; it < 4; ++it){
      int vv = tid + it * 256;
      int row = vv >> 4, cv = (vv & 15) * 8;
      *(bf16x8*)(Ks + row * 132 + cv) =
          *(const bf16x8*)(kb + (size_t)(kt64 + row) * DH + cv);
    }
    #pragma unroll
    for (int it = 0; it < 4; ++it){
      int vv = tid + it * 256;
      int d = vv >> 3, cv = (vv & 7) * 8;
      *(bf16x8*)(Vt + d * 68 + cv) =
          *(const bf16x8*)(vtb + (size_t)d * SS + kt64 + cv);
    }
    if (tid < 64) colbuf[tid] = 0.f;
    __syncthreads();
    f32x4 acc[2][4];
    #pragma unroll
    for (int i = 0; i < 2; ++i)
      #pragma unroll
      for (int j = 0; j < 4; ++j) acc[i][j] = (f32x4){0.f,0.f,0.f,0.f};
    #pragma unroll
    for (int ds = 0; ds < 4; ++ds){
      bf16x8 Bf[4];
      #pragma unroll
      for (int j = 0; j < 4; ++j)
        Bf[j] = *(const bf16x8*)(Ks + (j * 16 + m16) * 132 + ds * 32 + quad * 8);
      #pragma unroll
      for (int i = 0; i < 2; ++i)
        #pragma unroll
        for (int j = 0; j < 4; ++j)
          acc[i][j] = __builtin_amdgcn_mfma_f32_16x16x32_bf16(Qf[i][ds], Bf[j], acc[i][j], 0, 0, 0);
    }
    float mk2v[4];
    #pragma unroll
    for (int j = 0; j < 4; ++j) mk2v[j] = mk[kt64 + j * 16 + m16] * LOG2E;
    const bool full = (kt64 + 63 <= q0 + rbase);
    const bool has_sb = (kt64 == (SBI & ~63));
    float colpart[4] = {0.f, 0.f, 0.f, 0.f};
    #pragma unroll
    for (int i = 0; i < 2; ++i){
      #pragma unroll
      for (int r = 0; r < 4; ++r){
        const int qrow = q0 + rbase + i * 16 + quad * 4 + r;
        bf16x4 pk;
        float pv0 = 0.f;
        #pragma unroll
        for (int j = 0; j < 4; ++j){
          float pv = exp2f(acc[i][j][r] * SCALE2 + mk2v[j] - m_run[i][r]) * rl[i][r];
          if (!full && (kt64 + j * 16 + m16 > qrow)) pv = 0.f;
          colpart[j] += pv;
          pk[j] = (short)f2bf(pv);
          if (j == 0) pv0 = pv;
        }
        // row-major Ps[q][slot], slot = m16*4 + j (k-permuted; V^T uses same perm)
        *(bf16x4*)(Ps + (rbase + i * 16 + quad * 4 + r) * 68 + m16 * 4) = pk;
        if (has_sb && m16 == (SBI & 15))   // column SBI: j=0, m16=12 -> exact attn[:,SBI]
          acol[(size_t)bh * SS + qrow] = pv0;
      }
    }
    #pragma unroll
    for (int j = 0; j < 4; ++j){
      float c = colpart[j];
      c += __shfl_xor(c, 16);
      c += __shfl_xor(c, 32);
      if (quad == 0) atomicAdd(&colbuf[j * 16 + m16], c);
    }
    __syncthreads();   // Ps, Vt, colbuf complete
    #pragma unroll
    for (int ks = 0; ks < 2; ++ks){
      bf16x8 Af[2];
      #pragma unroll
      for (int i = 0; i < 2; ++i)
        Af[i] = *(const bf16x8*)(Ps + (rbase + i * 16 + m16) * 68 + ks * 32 + quad * 8);
      #pragma unroll
      for (int jd = 0; jd < 8; ++jd){
        bf16x8 Bf = *(const bf16x8*)(Vt + (jd * 16 + m16) * 68 + ks * 32 + quad * 8);
        #pragma unroll
        for (int i = 0; i < 2; ++i)
          o[i][jd] = __builtin_amdgcn_mfma_f32_16x16x32_bf16(Af[i], Bf, o[i][jd], 0, 0, 0);
      }
    }
    if (tid < 64){
      const float c = colbuf[tid];
      atomicAdd(colsum_all + h_ * SS + kt64 + tid, c);
      if (q0 == SS - NREC) atomicAdd(colsum_recent + h_ * SS + kt64 + tid, c);
    }
  }

  // epilogue: write O as bf16
  #pragma unroll
  for (int i = 0; i < 2; ++i){
    #pragma unroll
    for (int r = 0; r < 4; ++r){
      const int qrow = q0 + rbase + i * 16 + quad * 4 + r;
      unsigned short* orow = attn_out + (size_t)(b_ * SS + qrow) * HIDN + h_ * DH;
      #pragma unroll
      for (int jd = 0; jd < 8; ++jd)
        orow[jd * 16 + m16] = f2bf(o[i][jd][r]);
    }
  }
}

// ---------------- topk per head + score1 ---------------------------------------------------
__global__ __launch_bounds__(256) void k_topk(
    const float* __restrict__ colsum_all, const float* __restrict__ colsum_recent,
    const unsigned short* __restrict__ vg_, float* __restrict__ score1)
{
  __shared__ float vals[KEEPEND];
  __shared__ float rv[256];
  __shared__ int   ri[256];
  __shared__ int   sidx[NTOPK];
  __shared__ float sratio[NTOPK];
  const int h_ = blockIdx.x;
  const int tid = threadIdx.x;
  for (int i = SBI + tid; i < KEEPEND; i += 256) vals[i] = colsum_all[h_*SS + i];
  __syncthreads();
  for (int it = 0; it < NTOPK; ++it){
    float bv = -1.f; int bi = 0x7fffffff;
    for (int i = SBI + tid; i < KEEPEND; i += 256){
      float x = vals[i];
      if (x > bv){ bv = x; bi = i; }
    }
    rv[tid] = bv; ri[tid] = bi;
    __syncthreads();
    for (int s2 = 128; s2 > 0; s2 >>= 1){
      if (tid < s2){
        float ov = rv[tid + s2]; int oi = ri[tid + s2];
        if (ov > rv[tid] || (ov == rv[tid] && oi < ri[tid])){ rv[tid] = ov; ri[tid] = oi; }
      }
      __syncthreads();
    }
    if (tid == 0){ sidx[it] = ri[0]; vals[ri[0]] = -1.f; }
    __syncthreads();
  }
  if (tid < NTOPK) sratio[tid] = colsum_recent[h_*SS + sidx[tid]] * (1.f / NREC);
  __syncthreads();
  const int b_ = tid >> 7, d = tid & 127;
  float acc = 0.f;
  #pragma unroll
  for (int j = 0; j < NTOPK; ++j)
    acc += sratio[j] * bf2f(vg_[(size_t)((b_*NHH + h_)*SS + sidx[j])*DH + d]);
  score1[(b_*NHH + h_)*DH + d] = acc;
}

// ---------------- rank-1 correction on bf16 attn_out --------------------------------------
__global__ void k_corr(const float* __restrict__ acol, const float* __restrict__ score1,
                       const unsigned short* __restrict__ vg_, unsigned short* __restrict__ attn_out)
{
  const int idx = blockIdx.x * 256 + threadIdx.x;
  const int dq = idx & 31;
  int t = idx >> 5;
  const int qg = t & (SS - 1); t >>= 11;
  const int h_ = t & 15;
  const int b_ = t >> 4;
  if (qg < SBI) return;
  const float a = acol[(size_t)(b_*NHH + h_) * SS + qg];
  if (a == 0.f) return;
  const int d = dq * 4;
  const float4 s1 = *(const float4*)(score1 + (b_*NHH + h_) * DH + d);
  const ushort4_v vs = *(const ushort4_v*)(vg_ + (size_t)((b_*NHH + h_)*SS + SBI) * DH + d);
  ushort4_v* op = (ushort4_v*)(attn_out + (size_t)(b_*SS + qg) * HIDN + h_ * DH + d);
  ushort4_v ov = *op;
  ushort4_v nv;
  nv[0] = f2bf(bf2f(ov[0]) + a * (s1.x - bf2f(vs[0])));
  nv[1] = f2bf(bf2f(ov[1]) + a * (s1.y - bf2f(vs[1])));
  nv[2] = f2bf(bf2f(ov[2]) + a * (s1.z - bf2f(vs[2])));
  nv[3] = f2bf(bf2f(ov[3]) + a * (s1.w - bf2f(vs[3])));
  *op = nv;
}

extern "C" void kernel_launch(void* const* d_in, const int* in_sizes, int n_in,
                              void* d_out, int out_size, void* d_ws, size_t ws_size,
                              hipStream_t stream)
{
  (void)in_sizes; (void)n_in; (void)out_size; (void)ws_size;
  const float* hs    = (const float*)d_in[0];
  const float* amask = (const float*)d_in[1];
  const int*   pos   = (const int*)d_in[2];
  const float* Wqkv  = (const float*)d_in[3];
  const float* bqkv  = (const float*)d_in[4];
  const float* Wd    = (const float*)d_in[5];
  const float* bd    = (const float*)d_in[6];
  float* out = (float*)d_out;

  const size_t SZ   = (size_t)NB * NHH * SS * DH;   // 8,388,608
  const size_t NBHS = (size_t)NB * NHH * SS;        // 65,536
  const size_t HS   = (size_t)NHH * SS;             // 32,768

  float* colsum_all    = (float*)d_ws;
  float* colsum_recent = colsum_all + HS;
  float* acol          = colsum_recent + HS;
  float* score1        = acol + NBHS;
  unsigned short* attn_bf = (unsigned short*)(score1 + (size_t)NB*NHH*DH);
  unsigned short* q_bf  = attn_bf + SZ;
  unsigned short* k_bf  = q_bf + SZ;
  unsigned short* v_bf  = k_bf + SZ;
  unsigned short* vt_bf = v_bf + SZ;
  unsigned short* hs_bf = vt_bf + SZ;
  unsigned short* Wq_bf = hs_bf + SZ;
  unsigned short* Wd_bf = Wq_bf + (size_t)3*HIDN*HIDN;

  k_zero<<<256, 256, 0, stream>>>(colsum_all, (int)(2 * HS));
  k_f2bf<<<4096, 256, 0, stream>>>(hs,   hs_bf, (int)(SZ / 8));
  k_f2bf<<<6144, 256, 0, stream>>>(Wqkv, Wq_bf, (int)(3*HIDN*HIDN / 8));
  k_f2bf<<<2048, 256, 0, stream>>>(Wd,   Wd_bf, (int)(HIDN*HIDN / 8));

  k_gemm_qkv<<<dim3(48, 32), 256, 0, stream>>>(hs_bf, Wq_bf, bqkv, pos, q_bf, k_bf, v_bf);
  k_vt<<<dim3(32, 32), 256, 0, stream>>>(v_bf, vt_bf);

  k_fattn<<<512, 256, 0, stream>>>(q_bf, k_bf, vt_bf, amask,
                                   attn_bf, acol, colsum_all, colsum_recent);

  k_topk<<<NHH, 256, 0, stream>>>(colsum_all, colsum_recent, v_bf, score1);
  k_corr<<<(NB*NHH*SS*32)/256, 256, 0, stream>>>(acol, score1, v_bf, attn_bf);

  k_gemm_dense<<<dim3(16, 32), 256, 0, stream>>>(attn_bf, Wd_bf, bd, out);
}

// Round 5
// 561.528 us; speedup vs baseline: 1.4418x; 1.4418x over previous
//
#include <hip/hip_runtime.h>
#include <cfloat>
#include <math.h>

// Problem constants
#define NB 2
#define SS 2048
#define HIDN 2048
#define NHH 16
#define DH 128
#define SBI 204       // int(0.1*S)
#define KEEPEND 1844  // S - int(0.1*S)
#define NREC 128      // MERGE_BUDGET
#define NTOPK 16

typedef short bf16x8 __attribute__((ext_vector_type(8)));
typedef short bf16x4 __attribute__((ext_vector_type(4)));
typedef float f32x4  __attribute__((ext_vector_type(4)));
typedef unsigned short ushort8_v __attribute__((ext_vector_type(8)));
typedef unsigned short ushort4_v __attribute__((ext_vector_type(4)));

#define GLOBAL_AS __attribute__((address_space(1)))
#define LDS_AS    __attribute__((address_space(3)))

__device__ __forceinline__ void async16(const unsigned short* g, unsigned short* l){
  __builtin_amdgcn_global_load_lds((const GLOBAL_AS void*)g, (LDS_AS void*)l, 16, 0, 0);
}

__device__ __forceinline__ unsigned short f2bf(float x){
  union { float f; unsigned u; } cv; cv.f = x;
  unsigned u = cv.u;
  return (unsigned short)((u + 0x7fffu + ((u >> 16) & 1u)) >> 16);
}
__device__ __forceinline__ float bf2f(unsigned short u){
  union { unsigned u; float f; } cv; cv.u = ((unsigned)u) << 16;
  return cv.f;
}

__constant__ const float SCALE_QK = 0.08838834764831845f;   // 1/sqrt(128)
__constant__ const float SCALE2   = 0.12752551286084322f;   // SCALE_QK * log2(e)
__constant__ const float LOG2E    = 1.4426950408889634f;

__global__ void k_zero(float* __restrict__ p, int n){
  int i = blockIdx.x * 256 + threadIdx.x;
  if (i < n) p[i] = 0.f;
}

// ---------------- fp32 -> bf16 convert (8 elems/thread) -----------------------------------
__global__ void k_f2bf(const float* __restrict__ src, unsigned short* __restrict__ dst, int n8){
  int i = blockIdx.x * 256 + threadIdx.x;
  if (i >= n8) return;
  const float4* s = (const float4*)src + (size_t)i * 2;
  float4 a = s[0], b = s[1];
  ushort8_v r;
  r[0] = f2bf(a.x); r[1] = f2bf(a.y); r[2] = f2bf(a.z); r[3] = f2bf(a.w);
  r[4] = f2bf(b.x); r[5] = f2bf(b.y); r[6] = f2bf(b.z); r[7] = f2bf(b.w);
  *(ushort8_v*)(dst + (size_t)i * 8) = r;
}

// ---------------- bf16 MFMA GEMM: QKV variant, writes bf16 q/k/v with fused RoPE ----------
__global__ __launch_bounds__(256) void k_gemm_qkv(
    const unsigned short* __restrict__ A, const unsigned short* __restrict__ W,
    const float* __restrict__ bias, const int* __restrict__ pos,
    unsigned short* __restrict__ q, unsigned short* __restrict__ k,
    unsigned short* __restrict__ v)
{
  __shared__ __align__(16) unsigned short As[128 * 32];
  __shared__ __align__(16) unsigned short Bs[128 * 32];
  const int tid  = threadIdx.x;
  const int lane = tid & 63, w = tid >> 6;
  const int wm = w >> 1, wn = w & 1;
  const int quad = lane >> 4, m16 = lane & 15;
  const int cb   = blockIdx.x;
  const int row0 = blockIdx.y * 128;
  const int col0 = cb * 128;

  const int srow = tid >> 2;
  const int scol = (tid & 3) * 8;
  const unsigned short* ga = A + (size_t)(row0 + srow) * HIDN + scol;
  const unsigned short* gb = W + (size_t)(col0 + srow) * HIDN + scol;
  unsigned short* la = As + tid * 8;
  unsigned short* lb = Bs + tid * 8;

  f32x4 acc[4][4];
  #pragma unroll
  for (int i = 0; i < 4; ++i)
    #pragma unroll
    for (int j = 0; j < 4; ++j)
      acc[i][j] = (f32x4){0.f, 0.f, 0.f, 0.f};

  for (int k0 = 0; k0 < HIDN; k0 += 32){
    __syncthreads();
    async16(ga + k0,             la);
    async16(ga + k0 + 64 * HIDN, la + 64 * 32);
    async16(gb + k0,             lb);
    async16(gb + k0 + 64 * HIDN, lb + 64 * 32);
    __syncthreads();
    bf16x8 af[4], bf[4];
    #pragma unroll
    for (int j = 0; j < 4; ++j)
      bf[j] = *(const bf16x8*)(Bs + (wn * 64 + j * 16 + m16) * 32 + quad * 8);
    #pragma unroll
    for (int i = 0; i < 4; ++i)
      af[i] = *(const bf16x8*)(As + (wm * 64 + i * 16 + m16) * 32 + quad * 8);
    #pragma unroll
    for (int i = 0; i < 4; ++i)
      #pragma unroll
      for (int j = 0; j < 4; ++j)
        acc[i][j] = __builtin_amdgcn_mfma_f32_16x16x32_bf16(af[i], bf[j], acc[i][j], 0, 0, 0);
  }

  const int h  = cb / 3, r3 = cb - 3 * (cb / 3);
  unsigned short* dst = (r3 == 0) ? q : ((r3 == 1) ? k : v);
  const bool do_rope = (r3 < 2) && (wn == 0);
  const float invf = __expf(-(float)m16 * 0.5756462732485115f); // ln(10000)/16

  #pragma unroll
  for (int i = 0; i < 4; ++i){
    #pragma unroll
    for (int reg = 0; reg < 4; ++reg){
      const int mr = row0 + wm * 64 + i * 16 + quad * 4 + reg;
      const int b_ = mr >> 11, s_ = mr & (SS - 1);
      unsigned short* drow = dst + (size_t)((b_ * NHH + h) * SS + s_) * DH;
      float vals[4];
      #pragma unroll
      for (int j = 0; j < 4; ++j)
        vals[j] = acc[i][j][reg] + bias[col0 + wn * 64 + j * 16 + m16];
      if (do_rope){
        float sn, cs;
        const float p = (float)pos[b_ * SS + s_];
        sincosf(p * invf, &sn, &cs);
        const float x0 = vals[0], x1 = vals[1];
        vals[0] = x0 * cs - x1 * sn;
        vals[1] = x1 * cs + x0 * sn;
      }
      #pragma unroll
      for (int j = 0; j < 4; ++j)
        drow[wn * 64 + j * 16 + m16] = f2bf(vals[j]);
    }
  }
}

// Dense variant: C = A @ W^T + bias (A bf16, fp32 out)
__global__ __launch_bounds__(256) void k_gemm_dense(
    const unsigned short* __restrict__ A, const unsigned short* __restrict__ W,
    const float* __restrict__ bias, float* __restrict__ out)
{
  __shared__ __align__(16) unsigned short As[128 * 32];
  __shared__ __align__(16) unsigned short Bs[128 * 32];
  const int tid  = threadIdx.x;
  const int lane = tid & 63, w = tid >> 6;
  const int wm = w >> 1, wn = w & 1;
  const int quad = lane >> 4, m16 = lane & 15;
  const int row0 = blockIdx.y * 128;
  const int col0 = blockIdx.x * 128;

  const int srow = tid >> 2;
  const int scol = (tid & 3) * 8;
  const unsigned short* ga = A + (size_t)(row0 + srow) * HIDN + scol;
  const unsigned short* gb = W + (size_t)(col0 + srow) * HIDN + scol;
  unsigned short* la = As + tid * 8;
  unsigned short* lb = Bs + tid * 8;

  f32x4 acc[4][4];
  #pragma unroll
  for (int i = 0; i < 4; ++i)
    #pragma unroll
    for (int j = 0; j < 4; ++j)
      acc[i][j] = (f32x4){0.f, 0.f, 0.f, 0.f};

  for (int k0 = 0; k0 < HIDN; k0 += 32){
    __syncthreads();
    async16(ga + k0,             la);
    async16(ga + k0 + 64 * HIDN, la + 64 * 32);
    async16(gb + k0,             lb);
    async16(gb + k0 + 64 * HIDN, lb + 64 * 32);
    __syncthreads();
    bf16x8 af[4], bf[4];
    #pragma unroll
    for (int j = 0; j < 4; ++j)
      bf[j] = *(const bf16x8*)(Bs + (wn * 64 + j * 16 + m16) * 32 + quad * 8);
    #pragma unroll
    for (int i = 0; i < 4; ++i)
      af[i] = *(const bf16x8*)(As + (wm * 64 + i * 16 + m16) * 32 + quad * 8);
    #pragma unroll
    for (int i = 0; i < 4; ++i)
      #pragma unroll
      for (int j = 0; j < 4; ++j)
        acc[i][j] = __builtin_amdgcn_mfma_f32_16x16x32_bf16(af[i], bf[j], acc[i][j], 0, 0, 0);
  }

  #pragma unroll
  for (int i = 0; i < 4; ++i){
    #pragma unroll
    for (int reg = 0; reg < 4; ++reg){
      const int mr = row0 + wm * 64 + i * 16 + quad * 4 + reg;
      #pragma unroll
      for (int j = 0; j < 4; ++j){
        const int c = col0 + wn * 64 + j * 16 + m16;
        out[(size_t)mr * HIDN + c] = acc[i][j][reg] + bias[c];
      }
    }
  }
}

// ---------------- V transpose with k-permutation: Vt[bh][d][perm(s)] ----------------------
// perm within each 64-chunk: slot(k) = (k&15)*4 + (k>>4), k = s & 63.
__global__ __launch_bounds__(256) void k_vt(
    const unsigned short* __restrict__ v, unsigned short* __restrict__ vt)
{
  __shared__ unsigned short ld[64 * 136];
  const int tid = threadIdx.x;
  const int st = blockIdx.x;
  const int bh = blockIdx.y;
  const int s0 = st * 64;
  #pragma unroll
  for (int it = 0; it < 4; ++it){
    int vv = tid + it * 256;
    int row = vv >> 4, cv = (vv & 15) * 8;
    *(bf16x8*)(ld + row * 136 + cv) =
        *(const bf16x8*)(v + (size_t)(bh * SS + s0 + row) * DH + cv);
  }
  __syncthreads();
  const int d = tid >> 1, h2 = tid & 1;
  unsigned short* orow = vt + (size_t)(bh * DH + d) * SS + s0 + h2 * 32;
  #pragma unroll
  for (int g = 0; g < 4; ++g){
    ushort8_v pk;
    #pragma unroll
    for (int e = 0; e < 8; ++e){
      const int slot = h2 * 32 + g * 8 + e;
      const int kl = (slot & 3) * 16 + (slot >> 2);   // inverse perm
      pk[e] = ld[kl * 136 + d];
    }
    *(ushort8_v*)(orow + g * 8) = pk;
  }
}

// ---------------- Fused two-pass MFMA flash attention -------------------------------------
// 512 blocks flat; heavy-first + heavy/light pairing. 4 waves; wave w owns q rows
// [w*32, w*32+32). exp2-domain softmax, per-lane online (m,l), acol fused.
// NOTE: min-waves arg MUST be 2 — forcing 3 makes the allocator spill the 64-reg
// accumulator to scratch (R4: VGPR 124->84, WRITE_SIZE 36->218 MB, 1.7x regression).
// 3 blocks/CU still pack via LDS (52.2KB*3 <= 160KB) with VGPR ~124 < 170.
__global__ __launch_bounds__(256, 2) void k_fattn(
    const unsigned short* __restrict__ qg, const unsigned short* __restrict__ kg,
    const unsigned short* __restrict__ vtg, const float* __restrict__ amask,
    unsigned short* __restrict__ attn_out, float* __restrict__ acol,
    float* __restrict__ colsum_all, float* __restrict__ colsum_recent)
{
  __shared__ __align__(16) unsigned short Ks[64 * 132];
  __shared__ __align__(16) unsigned short Ps[128 * 68];
  __shared__ __align__(16) unsigned short Vt[128 * 68];
  __shared__ float colbuf[64];

  const int tid  = threadIdx.x;
  const int lane = tid & 63, w = tid >> 6;
  const int quad = lane >> 4, m16 = lane & 15;
  const int f = blockIdx.x;
  const int bh = f & 31;
  const int qt = (f < 256) ? (15 - (f >> 5)) : ((f - 256) >> 5);
  const int b_ = bh >> 4, h_ = bh & 15;
  const int q0 = qt * 128;
  const int rbase = w * 32;
  const unsigned short* qb  = qg  + (size_t)bh * SS * DH;
  const unsigned short* kb  = kg  + (size_t)bh * SS * DH;
  const unsigned short* vtb = vtg + (size_t)bh * DH * SS;
  const float* mk = amask + b_ * SS;
  const int nkt = 2 * qt + 2;

  // Q fragments in registers
  bf16x8 Qf[2][4];
  #pragma unroll
  for (int i = 0; i < 2; ++i)
    #pragma unroll
    for (int ds = 0; ds < 4; ++ds)
      Qf[i][ds] = *(const bf16x8*)(qb + (size_t)(q0 + rbase + i * 16 + m16) * DH + ds * 32 + quad * 8);

  // ---------------- pass A: per-lane online m,l (log2 domain) ----------------
  float m_ln[2][4], l_ln[2][4];
  #pragma unroll
  for (int i = 0; i < 2; ++i)
    #pragma unroll
    for (int r = 0; r < 4; ++r){ m_ln[i][r] = -FLT_MAX; l_ln[i][r] = 0.f; }

  for (int kt = 0; kt < nkt; ++kt){
    const int kt64 = kt * 64;
    __syncthreads();
    #pragma unroll
    for (int it = 0; it < 4; ++it){
      int vv = tid + it * 256;
      int row = vv >> 4, cv = (vv & 15) * 8;
      *(bf16x8*)(Ks + row * 132 + cv) =
          *(const bf16x8*)(kb + (size_t)(kt64 + row) * DH + cv);
    }
    __syncthreads();
    f32x4 acc[2][4];
    #pragma unroll
    for (int i = 0; i < 2; ++i)
      #pragma unroll
      for (int j = 0; j < 4; ++j) acc[i][j] = (f32x4){0.f,0.f,0.f,0.f};
    #pragma unroll
    for (int ds = 0; ds < 4; ++ds){
      bf16x8 Bf[4];
      #pragma unroll
      for (int j = 0; j < 4; ++j)
        Bf[j] = *(const bf16x8*)(Ks + (j * 16 + m16) * 132 + ds * 32 + quad * 8);
      #pragma unroll
      for (int i = 0; i < 2; ++i)
        #pragma unroll
        for (int j = 0; j < 4; ++j)
          acc[i][j] = __builtin_amdgcn_mfma_f32_16x16x32_bf16(Qf[i][ds], Bf[j], acc[i][j], 0, 0, 0);
    }
    float mk2v[4];
    #pragma unroll
    for (int j = 0; j < 4; ++j) mk2v[j] = mk[kt64 + j * 16 + m16] * LOG2E;
    const bool full = (kt64 + 63 <= q0 + rbase);
    #pragma unroll
    for (int i = 0; i < 2; ++i){
      #pragma unroll
      for (int r = 0; r < 4; ++r){
        float s[4];
        #pragma unroll
        for (int j = 0; j < 4; ++j) s[j] = acc[i][j][r] * SCALE2 + mk2v[j];
        if (!full){
          const int qrow = q0 + rbase + i * 16 + quad * 4 + r;
          #pragma unroll
          for (int j = 0; j < 4; ++j)
            if (kt64 + j * 16 + m16 > qrow) s[j] = -FLT_MAX;
        }
        float tmax = fmaxf(fmaxf(s[0], s[1]), fmaxf(s[2], s[3]));
        if (tmax > -1e37f){
          const float mn = fmaxf(m_ln[i][r], tmax);
          float ts = exp2f(s[0]-mn) + exp2f(s[1]-mn) + exp2f(s[2]-mn) + exp2f(s[3]-mn);
          l_ln[i][r] = l_ln[i][r] * exp2f(m_ln[i][r] - mn) + ts;
          m_ln[i][r] = mn;
        }
      }
    }
  }

  // cross-lane merge (4-step butterfly over the 16 column lanes)
  float m_run[2][4], rl[2][4];
  #pragma unroll
  for (int i = 0; i < 2; ++i)
    #pragma unroll
    for (int r = 0; r < 4; ++r){
      float m = m_ln[i][r], l = l_ln[i][r];
      #pragma unroll
      for (int d2 = 1; d2 < 16; d2 <<= 1){
        const float mo = __shfl_xor(m, d2);
        const float lo = __shfl_xor(l, d2);
        const float mn = fmaxf(m, mo);
        l = l * exp2f(m - mn) + lo * exp2f(mo - mn);
        m = mn;
      }
      m_run[i][r] = m;
      rl[i][r] = 1.f / l;
    }

  // ---------------- pass B: exact P, colsums, acol, PV ----------------
  f32x4 o[2][8];
  #pragma unroll
  for (int i = 0; i < 2; ++i)
    #pragma unroll
    for (int jd = 0; jd < 8; ++jd) o[i][jd] = (f32x4){0.f,0.f,0.f,0.f};

  for (int kt = 0; kt < nkt; ++kt){
    const int kt64 = kt * 64;
    __syncthreads();   // prev PV + colbuf flush done
    #pragma unroll
    for (int it = 0; it < 4; ++it){
      int vv = tid + it * 256;
      int row = vv >> 4, cv = (vv & 15) * 8;
      *(bf16x8*)(Ks + row * 132 + cv) =
          *(const bf16x8*)(kb + (size_t)(kt64 + row) * DH + cv);
    }
    #pragma unroll
    for (int it = 0; it < 4; ++it){
      int vv = tid + it * 256;
      int d = vv >> 3, cv = (vv & 7) * 8;
      *(bf16x8*)(Vt + d * 68 + cv) =
          *(const bf16x8*)(vtb + (size_t)d * SS + kt64 + cv);
    }
    if (tid < 64) colbuf[tid] = 0.f;
    __syncthreads();
    f32x4 acc[2][4];
    #pragma unroll
    for (int i = 0; i < 2; ++i)
      #pragma unroll
      for (int j = 0; j < 4; ++j) acc[i][j] = (f32x4){0.f,0.f,0.f,0.f};
    #pragma unroll
    for (int ds = 0; ds < 4; ++ds){
      bf16x8 Bf[4];
      #pragma unroll
      for (int j = 0; j < 4; ++j)
        Bf[j] = *(const bf16x8*)(Ks + (j * 16 + m16) * 132 + ds * 32 + quad * 8);
      #pragma unroll
      for (int i = 0; i < 2; ++i)
        #pragma unroll
        for (int j = 0; j < 4; ++j)
          acc[i][j] = __builtin_amdgcn_mfma_f32_16x16x32_bf16(Qf[i][ds], Bf[j], acc[i][j], 0, 0, 0);
    }
    float mk2v[4];
    #pragma unroll
    for (int j = 0; j < 4; ++j) mk2v[j] = mk[kt64 + j * 16 + m16] * LOG2E;
    const bool full = (kt64 + 63 <= q0 + rbase);
    const bool has_sb = (kt64 == (SBI & ~63));
    float colpart[4] = {0.f, 0.f, 0.f, 0.f};
    #pragma unroll
    for (int i = 0; i < 2; ++i){
      #pragma unroll
      for (int r = 0; r < 4; ++r){
        const int qrow = q0 + rbase + i * 16 + quad * 4 + r;
        bf16x4 pk;
        float pv0 = 0.f;
        #pragma unroll
        for (int j = 0; j < 4; ++j){
          float pv = exp2f(acc[i][j][r] * SCALE2 + mk2v[j] - m_run[i][r]) * rl[i][r];
          if (!full && (kt64 + j * 16 + m16 > qrow)) pv = 0.f;
          colpart[j] += pv;
          pk[j] = (short)f2bf(pv);
          if (j == 0) pv0 = pv;
        }
        // row-major Ps[q][slot], slot = m16*4 + j (k-permuted; V^T uses same perm)
        *(bf16x4*)(Ps + (rbase + i * 16 + quad * 4 + r) * 68 + m16 * 4) = pk;
        if (has_sb && m16 == (SBI & 15))   // column SBI: j=0, m16=12 -> exact attn[:,SBI]
          acol[(size_t)bh * SS + qrow] = pv0;
      }
    }
    #pragma unroll
    for (int j = 0; j < 4; ++j){
      float c = colpart[j];
      c += __shfl_xor(c, 16);
      c += __shfl_xor(c, 32);
      if (quad == 0) atomicAdd(&colbuf[j * 16 + m16], c);
    }
    __syncthreads();   // Ps, Vt, colbuf complete
    #pragma unroll
    for (int ks = 0; ks < 2; ++ks){
      bf16x8 Af[2];
      #pragma unroll
      for (int i = 0; i < 2; ++i)
        Af[i] = *(const bf16x8*)(Ps + (rbase + i * 16 + m16) * 68 + ks * 32 + quad * 8);
      #pragma unroll
      for (int jd = 0; jd < 8; ++jd){
        bf16x8 Bf = *(const bf16x8*)(Vt + (jd * 16 + m16) * 68 + ks * 32 + quad * 8);
        #pragma unroll
        for (int i = 0; i < 2; ++i)
          o[i][jd] = __builtin_amdgcn_mfma_f32_16x16x32_bf16(Af[i], Bf, o[i][jd], 0, 0, 0);
      }
    }
    if (tid < 64){
      const float c = colbuf[tid];
      atomicAdd(colsum_all + h_ * SS + kt64 + tid, c);
      if (q0 == SS - NREC) atomicAdd(colsum_recent + h_ * SS + kt64 + tid, c);
    }
  }

  // epilogue: write O as bf16
  #pragma unroll
  for (int i = 0; i < 2; ++i){
    #pragma unroll
    for (int r = 0; r < 4; ++r){
      const int qrow = q0 + rbase + i * 16 + quad * 4 + r;
      unsigned short* orow = attn_out + (size_t)(b_ * SS + qrow) * HIDN + h_ * DH;
      #pragma unroll
      for (int jd = 0; jd < 8; ++jd)
        orow[jd * 16 + m16] = f2bf(o[i][jd][r]);
    }
  }
}

// ---------------- topk per head + score1 ---------------------------------------------------
__global__ __launch_bounds__(256) void k_topk(
    const float* __restrict__ colsum_all, const float* __restrict__ colsum_recent,
    const unsigned short* __restrict__ vg_, float* __restrict__ score1)
{
  __shared__ float vals[KEEPEND];
  __shared__ float rv[256];
  __shared__ int   ri[256];
  __shared__ int   sidx[NTOPK];
  __shared__ float sratio[NTOPK];
  const int h_ = blockIdx.x;
  const int tid = threadIdx.x;
  for (int i = SBI + tid; i < KEEPEND; i += 256) vals[i] = colsum_all[h_*SS + i];
  __syncthreads();
  for (int it = 0; it < NTOPK; ++it){
    float bv = -1.f; int bi = 0x7fffffff;
    for (int i = SBI + tid; i < KEEPEND; i += 256){
      float x = vals[i];
      if (x > bv){ bv = x; bi = i; }
    }
    rv[tid] = bv; ri[tid] = bi;
    __syncthreads();
    for (int s2 = 128; s2 > 0; s2 >>= 1){
      if (tid < s2){
        float ov = rv[tid + s2]; int oi = ri[tid + s2];
        if (ov > rv[tid] || (ov == rv[tid] && oi < ri[tid])){ rv[tid] = ov; ri[tid] = oi; }
      }
      __syncthreads();
    }
    if (tid == 0){ sidx[it] = ri[0]; vals[ri[0]] = -1.f; }
    __syncthreads();
  }
  if (tid < NTOPK) sratio[tid] = colsum_recent[h_*SS + sidx[tid]] * (1.f / NREC);
  __syncthreads();
  const int b_ = tid >> 7, d = tid & 127;
  float acc = 0.f;
  #pragma unroll
  for (int j = 0; j < NTOPK; ++j)
    acc += sratio[j] * bf2f(vg_[(size_t)((b_*NHH + h_)*SS + sidx[j])*DH + d]);
  score1[(b_*NHH + h_)*DH + d] = acc;
}

// ---------------- rank-1 correction on bf16 attn_out --------------------------------------
__global__ void k_corr(const float* __restrict__ acol, const float* __restrict__ score1,
                       const unsigned short* __restrict__ vg_, unsigned short* __restrict__ attn_out)
{
  const int idx = blockIdx.x * 256 + threadIdx.x;
  const int dq = idx & 31;
  int t = idx >> 5;
  const int qg = t & (SS - 1); t >>= 11;
  const int h_ = t & 15;
  const int b_ = t >> 4;
  if (qg < SBI) return;
  const float a = acol[(size_t)(b_*NHH + h_) * SS + qg];
  if (a == 0.f) return;
  const int d = dq * 4;
  const float4 s1 = *(const float4*)(score1 + (b_*NHH + h_) * DH + d);
  const ushort4_v vs = *(const ushort4_v*)(vg_ + (size_t)((b_*NHH + h_)*SS + SBI) * DH + d);
  ushort4_v* op = (ushort4_v*)(attn_out + (size_t)(b_*SS + qg) * HIDN + h_ * DH + d);
  ushort4_v ov = *op;
  ushort4_v nv;
  nv[0] = f2bf(bf2f(ov[0]) + a * (s1.x - bf2f(vs[0])));
  nv[1] = f2bf(bf2f(ov[1]) + a * (s1.y - bf2f(vs[1])));
  nv[2] = f2bf(bf2f(ov[2]) + a * (s1.z - bf2f(vs[2])));
  nv[3] = f2bf(bf2f(ov[3]) + a * (s1.w - bf2f(vs[3])));
  *op = nv;
}

extern "C" void kernel_launch(void* const* d_in, const int* in_sizes, int n_in,
                              void* d_out, int out_size, void* d_ws, size_t ws_size,
                              hipStream_t stream)
{
  (void)in_sizes; (void)n_in; (void)out_size; (void)ws_size;
  const float* hs    = (const float*)d_in[0];
  const float* amask = (const float*)d_in[1];
  const int*   pos   = (const int*)d_in[2];
  const float* Wqkv  = (const float*)d_in[3];
  const float* bqkv  = (const float*)d_in[4];
  const float* Wd    = (const float*)d_in[5];
  const float* bd    = (const float*)d_in[6];
  float* out = (float*)d_out;

  const size_t SZ   = (size_t)NB * NHH * SS * DH;   // 8,388,608
  const size_t NBHS = (size_t)NB * NHH * SS;        // 65,536
  const size_t HS   = (size_t)NHH * SS;             // 32,768

  float* colsum_all    = (float*)d_ws;
  float* colsum_recent = colsum_all + HS;
  float* acol          = colsum_recent + HS;
  float* score1        = acol + NBHS;
  unsigned short* attn_bf = (unsigned short*)(score1 + (size_t)NB*NHH*DH);
  unsigned short* q_bf  = attn_bf + SZ;
  unsigned short* k_bf  = q_bf + SZ;
  unsigned short* v_bf  = k_bf + SZ;
  unsigned short* vt_bf = v_bf + SZ;
  unsigned short* hs_bf = vt_bf + SZ;
  unsigned short* Wq_bf = hs_bf + SZ;
  unsigned short* Wd_bf = Wq_bf + (size_t)3*HIDN*HIDN;

  k_zero<<<256, 256, 0, stream>>>(colsum_all, (int)(2 * HS));
  k_f2bf<<<4096, 256, 0, stream>>>(hs,   hs_bf, (int)(SZ / 8));
  k_f2bf<<<6144, 256, 0, stream>>>(Wqkv, Wq_bf, (int)(3*HIDN*HIDN / 8));
  k_f2bf<<<2048, 256, 0, stream>>>(Wd,   Wd_bf, (int)(HIDN*HIDN / 8));

  k_gemm_qkv<<<dim3(48, 32), 256, 0, stream>>>(hs_bf, Wq_bf, bqkv, pos, q_bf, k_bf, v_bf);
  k_vt<<<dim3(32, 32), 256, 0, stream>>>(v_bf, vt_bf);

  k_fattn<<<512, 256, 0, stream>>>(q_bf, k_bf, vt_bf, amask,
                                   attn_bf, acol, colsum_all, colsum_recent);

  k_topk<<<NHH, 256, 0, stream>>>(colsum_all, colsum_recent, v_bf, score1);
  k_corr<<<(NB*NHH*SS*32)/256, 256, 0, stream>>>(acol, score1, v_bf, attn_bf);

  k_gemm_dense<<<dim3(16, 32), 256, 0, stream>>>(attn_bf, Wd_bf, bd, out);
}